// Round 4
// baseline (364.585 us; speedup 1.0000x reference)
//
#include <hip/hip_runtime.h>
#include <math.h>

// ---------------- complex helpers ----------------
__device__ inline float2 cmul(float2 a, float2 b){
  return make_float2(a.x*b.x - a.y*b.y, a.x*b.y + a.y*b.x);
}
__device__ inline void cfma(float2& acc, float2 a, float2 b){
  acc.x += a.x*b.x - a.y*b.y;
  acc.y += a.x*b.y + a.y*b.x;
}

// u3(th, ph, lam) = [[c, -e^{i lam} s], [e^{i ph} s, e^{i(ph+lam)} c]]
__device__ inline void mk_u3(const float* p, float2& u00, float2& u01, float2& u10, float2& u11){
  float s, c;   sincosf(0.5f*p[0], &s, &c);
  float sl, cl; sincosf(p[1], &sl, &cl);            // ph
  float sm, cm; sincosf(p[2], &sm, &cm);            // lam
  float s2, c2; sincosf(p[1] + p[2], &s2, &c2);     // ph+lam
  u00 = make_float2(c, 0.f);
  u01 = make_float2(-s*cm, -s*sm);
  u10 = make_float2( s*cl,  s*sl);
  u11 = make_float2( c*c2,  c*s2);
}

__device__ inline void pauli2(int t, float2* m){ // 2x2, m[i*2+j]
  if (t == 0){ m[0]=make_float2(1,0); m[1]=make_float2(0,0);  m[2]=make_float2(0,0); m[3]=make_float2(1,0); }
  else if (t == 1){ m[0]=make_float2(0,0); m[1]=make_float2(1,0);  m[2]=make_float2(1,0); m[3]=make_float2(0,0); }
  else if (t == 2){ m[0]=make_float2(0,0); m[1]=make_float2(0,-1); m[2]=make_float2(0,1); m[3]=make_float2(0,0); }
  else            { m[0]=make_float2(1,0); m[1]=make_float2(0,0);  m[2]=make_float2(0,0); m[3]=make_float2(-1,0);}
}

// ---------------- gate program (base gates, build-only) ----------------
// types: 0=U3(w1), 1=ZZ(w1,w2), 2=YY, 3=XX, 4=CU3(ctrl=w1,tgt=w2), 5=PAULI kron wires(0,4), w1/w2 = pauli ids
// poff: <1000 conv, 1000..1999 pool-1000, >=2000 last-2000
struct GSpec { int type; int w1; int w2; int poff; };
#define NG 66
__device__ const GSpec gspec[NG] = {
  {0,0,0,  0},{0,2,0, 33},{1,0,2,  6},{2,0,2,  7},{3,0,2,  8},{0,0,0,  9},{0,2,0, 42},
  {0,1,0, 15},{0,3,0, 48},{1,1,3, 21},{2,1,3, 22},{3,1,3, 23},{0,1,0, 24},{0,3,0, 57},
  {0,4,0, 60},{0,6,0, 93},{1,4,6, 66},{2,4,6, 67},{3,4,6, 68},{0,4,0, 69},{0,6,0,102},
  {0,5,0, 75},{0,7,0,108},{1,5,7, 81},{2,5,7, 82},{3,5,7, 83},{0,5,0, 84},{0,7,0,117},
  {4,1,0,1000},{4,3,2,1003},{4,5,4,1006},{4,7,6,1009},
  {0,0,0,120},{0,2,0,153},{1,0,2,126},{2,0,2,127},{3,0,2,128},{0,0,0,129},{0,2,0,162},
  {0,4,0,180},{0,4,0,183},{0,4,0,186},{0,4,0,189},{0,4,0,192},
  {0,6,0,210},{0,6,0,213},{0,6,0,216},{0,6,0,219},{0,6,0,222},
  {4,2,0,1012},{4,6,4,1015},
  {5,1,0,2000},{5,2,0,2001},{5,3,0,2002},{5,3,1,2003},{5,0,1,2004},
  {5,1,1,2005},{5,2,1,2006},{5,2,2,2007},{5,3,2,2008},{5,0,2,2009},
  {5,1,2,2010},{5,1,3,2011},{5,2,3,2012},{5,3,3,2013},{5,0,3,2014},
};

// ---------------- 256-thread state-vector engine (S + gates in LDS) ----------------
// Wire w maps to bit (7-w) of the 256-index (wire 0 = MSB).
__device__ inline void apply1q_b(float2* S, int tid, int bit,
                                 float2 u00, float2 u01, float2 u10, float2 u11){
  if (tid < 128){
    int p  = tid;
    int k0 = ((p >> bit) << (bit+1)) | (p & ((1<<bit)-1));
    int k1 = k0 | (1 << bit);
    float2 a = S[k0], b = S[k1];
    float2 na = make_float2(u00.x*a.x - u00.y*a.y + u01.x*b.x - u01.y*b.y,
                            u00.x*a.y + u00.y*a.x + u01.x*b.y + u01.y*b.x);
    float2 nb = make_float2(u10.x*a.x - u10.y*a.y + u11.x*b.x - u11.y*b.y,
                            u10.x*a.y + u10.y*a.x + u11.x*b.y + u11.y*b.x);
    S[k0] = na; S[k1] = nb;
  }
  __syncthreads();
}

__device__ inline void apply2q_b(float2* S, int tid, int bitA, int bitB, const float2* G){
  if (tid < 64){
    int lane = tid;
    int hi = bitA > bitB ? bitA : bitB;
    int lo = bitA ^ bitB ^ hi;
    int t2  = ((lane >> lo) << (lo+1)) | (lane & ((1<<lo)-1));
    int k00 = ((t2   >> hi) << (hi+1)) | (t2   & ((1<<hi)-1));
    int mA = 1 << bitA, mB = 1 << bitB;
    int id[4] = { k00, k00|mB, k00|mA, k00|mA|mB };
    float2 v[4];
    #pragma unroll
    for (int r = 0; r < 4; r++) v[r] = S[id[r]];
    #pragma unroll
    for (int r = 0; r < 4; r++){
      float re = 0.f, im = 0.f;
      #pragma unroll
      for (int c = 0; c < 4; c++){
        float2 g = G[r*4 + c];
        re += g.x*v[c].x - g.y*v[c].y;
        im += g.x*v[c].y + g.y*v[c].x;
      }
      S[id[r]] = make_float2(re, im);
    }
  }
  __syncthreads();
}

// Kernel A: blocks 0..1023 = gemv (reduced = tanh(x @ fc_w^T + b));
//           blocks 1024..1279 = sim (block j simulates e_j; U[k*256+j] = amp k).
// sim hides under the HBM-bound gemv instead of serializing ahead of it.
// LDS union: gemv 24 KiB tile / sim ~13 KiB (Gt+Ft+Ms+S) -> 5 blocks/CU fits (120 KiB).
__global__ __launch_bounds__(256) void kern_a(const float* __restrict__ x,
                                              const float* __restrict__ w,
                                              const float* __restrict__ b,
                                              const float* __restrict__ conv,
                                              const float* __restrict__ pool,
                                              const float* __restrict__ last,
                                              float* __restrict__ red,
                                              float2* __restrict__ U){
  __shared__ float4 smem4[1536];             // 24 KiB union
  const int tid = threadIdx.x;

  if (blockIdx.x < 1024){
    // ================= gemv =================
    float4* wl = smem4;                      // [8][192] float4, one K-quarter of w
    const int wave = tid >> 6, lane = tid & 63;
    const int rl = lane >> 5, co = lane & 31;
    const int row0 = blockIdx.x*16 + wave*4 + rl*2;   // rows row0, row0+1
    const float4* xp0 = (const float4*)(x + (size_t)row0*3072);
    const float4* xp1 = (const float4*)(x + (size_t)(row0+1)*3072);
    const float4* wp  = (const float4*)w;    // [8][768] float4
    float accA[8], accB[8];
    #pragma unroll
    for (int q = 0; q < 8; q++){ accA[q] = 0.f; accB[q] = 0.f; }

    for (int qt = 0; qt < 4; qt++){
      __syncthreads();
      #pragma unroll
      for (int i = 0; i < 6; i++){
        int idx = tid + 256*i;               // 0..1535
        int q = idx / 192, cc = idx - q*192;
        wl[idx] = wp[q*768 + qt*192 + cc];
      }
      __syncthreads();
      #pragma unroll
      for (int it = 0; it < 6; it++){
        int cl = it*32 + co;                 // 0..191 within tile
        float4 xa = xp0[qt*192 + cl];
        float4 xb = xp1[qt*192 + cl];
        #pragma unroll
        for (int q = 0; q < 8; q++){
          float4 wv = wl[q*192 + cl];
          accA[q] += wv.x*xa.x + wv.y*xa.y + wv.z*xa.z + wv.w*xa.w;
          accB[q] += wv.x*xb.x + wv.y*xb.y + wv.z*xb.z + wv.w*xb.w;
        }
      }
    }

    #pragma unroll
    for (int q = 0; q < 8; q++){
      float va = accA[q], vb = accB[q];
      va += __shfl_xor(va, 1);  vb += __shfl_xor(vb, 1);
      va += __shfl_xor(va, 2);  vb += __shfl_xor(vb, 2);
      va += __shfl_xor(va, 4);  vb += __shfl_xor(vb, 4);
      va += __shfl_xor(va, 8);  vb += __shfl_xor(vb, 8);
      va += __shfl_xor(va, 16); vb += __shfl_xor(vb, 16);
      accA[q] = va; accB[q] = vb;
    }
    if (co == 0){
      float4 a0 = make_float4(tanhf(accA[0]+b[0]), tanhf(accA[1]+b[1]),
                              tanhf(accA[2]+b[2]), tanhf(accA[3]+b[3]));
      float4 a1 = make_float4(tanhf(accA[4]+b[4]), tanhf(accA[5]+b[5]),
                              tanhf(accA[6]+b[6]), tanhf(accA[7]+b[7]));
      float4* rpA = (float4*)(red + (size_t)row0*8);
      rpA[0] = a0; rpA[1] = a1;
      float4 b0 = make_float4(tanhf(accB[0]+b[0]), tanhf(accB[1]+b[1]),
                              tanhf(accB[2]+b[2]), tanhf(accB[3]+b[3]));
      float4 b1 = make_float4(tanhf(accB[4]+b[4]), tanhf(accB[5]+b[5]),
                              tanhf(accB[6]+b[6]), tanhf(accB[7]+b[7]));
      float4* rpB = (float4*)(red + (size_t)(row0+1)*8);
      rpB[0] = b0; rpB[1] = b1;
    }
    return;
  }

  // ================= sim =================
  const int j = blockIdx.x - 1024;
  float2* Gt = (float2*)smem4;               // 66*16
  float2* Ft = Gt + NG*16;                   // 14*16: 0-3 C0..C3, 4 C4, 5 S0, 6 S1, 7-12 P0..P5, 13 L
  float2* Ms = Ft + 14*16;                   // 7*16 scratch
  float2* S  = Ms + 7*16;                    // 256 amplitudes

  // ---- build all base gate matrices into LDS ----
  for (int g = tid; g < NG; g += 256){
    GSpec sp = gspec[g];
    const float* base;
    if (sp.poff >= 2000)      base = last + (sp.poff - 2000);
    else if (sp.poff >= 1000) base = pool + (sp.poff - 1000);
    else                      base = conv + sp.poff;
    float2 G[16];
    #pragma unroll
    for (int i = 0; i < 16; i++) G[i] = make_float2(0.f, 0.f);
    if (sp.type == 0){
      float2 a,bb,c,d; mk_u3(base,a,bb,c,d);
      G[0]=a; G[1]=bb; G[2]=c; G[3]=d;
    } else if (sp.type == 1){ // ZZ
      float s,co; sincosf(0.5f*base[0], &s, &co);
      G[0]=make_float2(co,-s); G[5]=make_float2(co,s); G[10]=make_float2(co,s); G[15]=make_float2(co,-s);
    } else if (sp.type == 2){ // YY
      float s,co; sincosf(0.5f*base[0], &s, &co);
      G[0]=G[5]=G[10]=G[15]=make_float2(co,0.f);
      G[3]=make_float2(0.f,s); G[6]=make_float2(0.f,-s); G[9]=make_float2(0.f,-s); G[12]=make_float2(0.f,s);
    } else if (sp.type == 3){ // XX
      float s,co; sincosf(0.5f*base[0], &s, &co);
      G[0]=G[5]=G[10]=G[15]=make_float2(co,0.f);
      G[3]=G[6]=G[9]=G[12]=make_float2(0.f,-s);
    } else if (sp.type == 4){ // CU3
      float2 a,bb,c,d; mk_u3(base,a,bb,c,d);
      G[0]=make_float2(1.f,0.f); G[5]=make_float2(1.f,0.f);
      G[10]=a; G[11]=bb; G[14]=c; G[15]=d;
    } else { // PAULI word: G = cos*I - i sin*(A ⊗ B)
      float s,co; sincosf(0.5f*base[0], &s, &co);
      float2 A2[4], B2[4]; pauli2(sp.w1,A2); pauli2(sp.w2,B2);
      #pragma unroll
      for (int i1 = 0; i1 < 2; i1++)
      #pragma unroll
      for (int i2 = 0; i2 < 2; i2++)
      #pragma unroll
      for (int j1 = 0; j1 < 2; j1++)
      #pragma unroll
      for (int j2 = 0; j2 < 2; j2++){
        float2 Pv = cmul(A2[i1*2+j1], B2[i2*2+j2]);
        int rr = i1*2+i2, cc = j1*2+j2;
        G[rr*4+cc] = make_float2((rr==cc ? co : 0.f) + s*Pv.y, -s*Pv.x);
      }
    }
    #pragma unroll
    for (int i = 0; i < 16; i++) Gt[g*16 + i] = G[i];
  }
  __syncthreads();

  const int fe = tid & 15;
  const int fr = fe >> 2, fc = fe & 3;

  // ---- fusion sub-phase 1: L1 conv pairs (threads 0..63, pair p = tid>>4) ----
  {
    const bool act = tid < 64;
    const int p  = tid >> 4;
    const int gb = p*7;
    if (act){
      float2 va = Gt[gb*16     + (fr>>1)*2 + (fc>>1)];
      float2 vb = Gt[(gb+1)*16 + (fr&1)*2  + (fc&1)];
      Ms[p*16 + fe] = cmul(va, vb);
    }
    __syncthreads();
    for (int s = 0; s < 3; s++){
      float2 acc = make_float2(0.f, 0.f);
      if (act){
        #pragma unroll
        for (int k = 0; k < 4; k++)
          cfma(acc, Gt[(gb+2+s)*16 + fr*4 + k], Ms[p*16 + k*4 + fc]);
      }
      __syncthreads();
      if (act) Ms[p*16 + fe] = acc;
      __syncthreads();
    }
    if (act){
      float2 ka = Gt[(gb+5)*16 + (fr>>1)*2 + (fc>>1)];
      float2 kb = Gt[(gb+6)*16 + (fr&1)*2  + (fc&1)];
      Ft[p*16 + fe] = cmul(ka, kb);
    }
    __syncthreads();
    float2 acc2 = make_float2(0.f, 0.f);
    if (act){
      #pragma unroll
      for (int k = 0; k < 4; k++)
        cfma(acc2, Ft[p*16 + fr*4 + k], Ms[p*16 + k*4 + fc]);
    }
    __syncthreads();
    if (act) Ft[p*16 + fe] = acc2;
    __syncthreads();
  }

  // ---- fusion sub-phase 2 (concurrent groups):
  //   tid 0-15: C4 (g32..g38); tid 16-31: L (g51..g65); tid 32-39: S0/S1 (g39..g48)
  {
    const int grp = tid >> 4;
    if (grp == 0){
      float2 va = Gt[32*16 + (fr>>1)*2 + (fc>>1)];
      float2 vb = Gt[33*16 + (fr&1)*2  + (fc&1)];
      Ms[4*16 + fe] = cmul(va, vb);
    } else if (grp == 1){
      Ms[5*16 + fe] = Gt[51*16 + fe];
    } else if (tid < 40){
      int t = (tid-32)>>2, e2 = (tid-32)&3;
      Ms[6*16 + t*4 + e2] = Gt[(39+5*t)*16 + e2];
    }
    __syncthreads();
    for (int s = 1; s <= 14; s++){
      float2 val = make_float2(0.f, 0.f);
      int wf = 0, dst = 0;   // wf: 1 -> Ms, 2 -> Ft
      if (grp == 0){
        if (s <= 3){            // ZZ (g34), YY (g35), XX (g36)
          #pragma unroll
          for (int k = 0; k < 4; k++)
            cfma(val, Gt[(33+s)*16 + fr*4 + k], Ms[4*16 + k*4 + fc]);
          wf = 1; dst = 4*16 + fe;
        } else if (s == 4){     // K2 = kron(g37, g38) -> temp in Ms[0]
          float2 ka = Gt[37*16 + (fr>>1)*2 + (fc>>1)];
          float2 kb = Gt[38*16 + (fr&1)*2  + (fc&1)];
          val = cmul(ka, kb); wf = 1; dst = 0*16 + fe;
        } else if (s == 5){     // C4 = K2 * M
          #pragma unroll
          for (int k = 0; k < 4; k++)
            cfma(val, Ms[0*16 + fr*4 + k], Ms[4*16 + k*4 + fc]);
          wf = 2; dst = 4*16 + fe;
        }
      } else if (grp == 1){     // L = g65 * ... * g51
        #pragma unroll
        for (int k = 0; k < 4; k++)
          cfma(val, Gt[(51+s)*16 + fr*4 + k], Ms[5*16 + k*4 + fc]);
        if (s == 14){ wf = 2; dst = 13*16 + fe; }
        else        { wf = 1; dst = 5*16 + fe; }
      } else if (tid < 40 && s <= 4){  // 2x2 chains, wires 4 and 6
        int t = (tid-32)>>2, e2 = (tid-32)&3, r2 = e2>>1, c2 = e2&1;
        #pragma unroll
        for (int k = 0; k < 2; k++)
          cfma(val, Gt[(39+5*t+s)*16 + r2*2 + k], Ms[6*16 + t*4 + k*2 + c2]);
        if (s == 4){ wf = 2; dst = (5+t)*16 + e2; }
        else       { wf = 1; dst = 6*16 + t*4 + e2; }
      }
      __syncthreads();
      if (wf == 1) Ms[dst] = val;
      else if (wf == 2) Ft[dst] = val;
      __syncthreads();
    }
    // CU3 copies: Ft slots 7..12 <- Gt {28,29,30,31,49,50}
    for (int idx = tid; idx < 96; idx += 256){
      int q = idx >> 4, e = idx & 15;
      int gid = (q < 4) ? (28+q) : (q == 4 ? 49 : 50);
      Ft[(7+q)*16 + e] = Gt[gid*16 + e];
    }
  }
  __syncthreads();

  // ---- state init ----
  S[tid] = make_float2(tid==j ? 1.f : 0.f, 0.f);
  __syncthreads();

  // ---- 14 fused applies (original gate order preserved; disjoint-wire gates commute) ----
  apply2q_b(S, tid, 7, 5, &Ft[0*16]);   // C0 (0,2)
  apply2q_b(S, tid, 6, 4, &Ft[1*16]);   // C1 (1,3)
  apply2q_b(S, tid, 3, 1, &Ft[2*16]);   // C2 (4,6)
  apply2q_b(S, tid, 2, 0, &Ft[3*16]);   // C3 (5,7)
  apply2q_b(S, tid, 6, 7, &Ft[7*16]);   // P0 CU3(1,0)
  apply2q_b(S, tid, 4, 5, &Ft[8*16]);   // P1 CU3(3,2)
  apply2q_b(S, tid, 2, 3, &Ft[9*16]);   // P2 CU3(5,4)
  apply2q_b(S, tid, 0, 1, &Ft[10*16]);  // P3 CU3(7,6)
  apply2q_b(S, tid, 7, 5, &Ft[4*16]);   // C4 (0,2)
  apply1q_b(S, tid, 3, Ft[5*16+0], Ft[5*16+1], Ft[5*16+2], Ft[5*16+3]);  // S0 wire 4
  apply1q_b(S, tid, 1, Ft[6*16+0], Ft[6*16+1], Ft[6*16+2], Ft[6*16+3]);  // S1 wire 6
  apply2q_b(S, tid, 5, 7, &Ft[11*16]);  // P4 CU3(2,0)
  apply2q_b(S, tid, 1, 3, &Ft[12*16]);  // P5 CU3(6,4)
  apply2q_b(S, tid, 7, 3, &Ft[13*16]);  // L (0,4)

  U[tid*256 + j] = S[tid];
}

// K2: block xm: D[i] = sum_k z_k Re(conj(U_ki) U_k(i^xm)); FWHT over i; store PADDED m table:
// layout mt[(h*27+mm)*32 + l] (h=3d7+d6, mm=9d5+3d4+d3, l=9d2+3d1+d0) -> per-bit weights
// {1,3,9,32,96,288,864,2592}. Pads (l=27..31) zeroed so contract can read raw float4s.
__global__ __launch_bounds__(256) void kern_m2(const float2* __restrict__ U,
                                               float* __restrict__ mt){
  __shared__ float dsh[256];
  const int xm = blockIdx.x, i = threadIdx.x;
  if (xm == 0){                      // zero the 9*27*5 pad slots (poison otherwise)
    for (int z = i; z < 1215; z += 256){
      int hm = z/5, l = z - hm*5;
      mt[hm*32 + 27 + l] = 0.f;
    }
  }
  const int j2 = i ^ xm;
  float acc = 0.f;
  #pragma unroll 4
  for (int k = 0; k < 128; k++){
    float2 ui0 = U[k*256 + i];
    float2 uj0 = U[k*256 + j2];
    float2 ui1 = U[(k+128)*256 + i];
    float2 uj1 = U[(k+128)*256 + j2];
    acc += (ui0.x*uj0.x + ui0.y*uj0.y) - (ui1.x*uj1.x + ui1.y*uj1.y);
  }
  dsh[i] = acc;
  __syncthreads();
  for (int bit = 1; bit < 256; bit <<= 1){
    float mine = dsh[i], other = dsh[i ^ bit];
    __syncthreads();
    dsh[i] = (i & bit) ? (other - mine) : (mine + other);
    __syncthreads();
  }
  if ((i & xm) == 0){
    int idx = 0;
    #pragma unroll
    for (int b2 = 0; b2 < 8; b2++){
      const int w8 = (b2==0)?1:(b2==1)?3:(b2==2)?9:(b2==3)?32:
                     (b2==4)?96:(b2==5)?288:(b2==6)?864:2592;
      int dg = ((xm >> b2) & 1) ? 1 : (((i >> b2) & 1) ? 2 : 0);
      idx += dg * w8;
    }
    mt[idx] = dsh[i] * (1.0f/256.0f);
  }
}

// K4: z0[e] = sum over 3^8 Pauli strings m_p * prod t_w; logits = z0*fow + fob.
// mt (31 KB) read directly from global: wave-uniform addresses broadcast through L1
// (~4 cyc/inst issue) instead of the 12 cyc/inst LDS pipe that bound the old version.
__global__ __launch_bounds__(256) void kern_contract(const float* __restrict__ red,
                                                     const float* __restrict__ mt,
                                                     const float* __restrict__ fow,
                                                     const float* __restrict__ fob,
                                                     float* __restrict__ out){
  __shared__ float zsh[4*64];
  const int tid = threadIdx.x;
  const int wave = tid >> 6, lane = tid & 63;
  const int e = blockIdx.x*64 + lane;
  const float4* rp = (const float4*)(red + (size_t)e*8);
  float4 r0 = rp[0], r1 = rp[1];

  float rr[8] = {r0.x, r0.y, r0.z, r0.w, r1.x, r1.y, r1.z, r1.w};
  float sn[8], cs[8];
  #pragma unroll
  for (int q = 0; q < 8; q++) sincosf(rr[q], &sn[q], &cs[q]);
  // digit d at bit b: 0 -> 1, 1 -> sin(r[7-b]) (X), 2 -> cos(r[7-b]) (Z)
  float f0[3] = {1.f, sn[7], cs[7]};
  float f1[3] = {1.f, sn[6], cs[6]};
  float f2[3] = {1.f, sn[5], cs[5]};
  float g27[32];
  #pragma unroll
  for (int z = 27; z < 32; z++) g27[z] = 0.f;
  #pragma unroll
  for (int d2 = 0; d2 < 3; d2++)
  #pragma unroll
  for (int d1 = 0; d1 < 3; d1++)
  #pragma unroll
  for (int d0 = 0; d0 < 3; d0++)
    g27[9*d2 + 3*d1 + d0] = f2[d2]*f1[d1]*f0[d0];
  float4 glo4[8];
  #pragma unroll
  for (int v = 0; v < 8; v++)
    glo4[v] = make_float4(g27[4*v], g27[4*v+1], g27[4*v+2], g27[4*v+3]);
  float f3[3] = {1.f, sn[4], cs[4]};
  float f4[3] = {1.f, sn[3], cs[3]};
  float f5[3] = {1.f, sn[2], cs[2]};
  float gmid[27];
  #pragma unroll
  for (int d5 = 0; d5 < 3; d5++)
  #pragma unroll
  for (int d4 = 0; d4 < 3; d4++)
  #pragma unroll
  for (int d3 = 0; d3 < 3; d3++)
    gmid[9*d5 + 3*d4 + d3] = f5[d5]*f4[d4]*f3[d3];
  float f6[3] = {1.f, sn[1], cs[1]};
  float f7[3] = {1.f, sn[0], cs[0]};
  float ghi[9];
  #pragma unroll
  for (int d7 = 0; d7 < 3; d7++)
  #pragma unroll
  for (int d6 = 0; d6 < 3; d6++)
    ghi[3*d7 + d6] = f7[d7]*f6[d6];

  // wave h-partition: {0,1,2},{3,4},{5,6},{7,8}
  const int hbeg = (wave==0) ? 0 : (wave==1) ? 3 : (wave==2) ? 5 : 7;
  const int hend = hbeg + ((wave==0) ? 3 : 2);
  float part = 0.f;
  for (int h = hbeg; h < hend; h++){
    float ha = 0.f, hb = 0.f;
    #pragma unroll 3
    for (int mm = 0; mm < 27; mm++){
      const float4* mp = (const float4*)(mt + (size_t)((h*27 + mm) << 5));
      float d0 = 0.f, d1 = 0.f;
      #pragma unroll
      for (int v = 0; v < 8; v += 2){
        float4 m0 = mp[v], m1 = mp[v+1];
        d0 += m0.x*glo4[v].x   + m0.y*glo4[v].y   + m0.z*glo4[v].z   + m0.w*glo4[v].w;
        d1 += m1.x*glo4[v+1].x + m1.y*glo4[v+1].y + m1.z*glo4[v+1].z + m1.w*glo4[v+1].w;
      }
      float term = (d0 + d1) * gmid[mm];
      if (mm & 1) hb += term; else ha += term;
    }
    part += (ha + hb) * ghi[h];
  }
  zsh[wave*64 + lane] = part;
  __syncthreads();

  for (int idx = tid; idx < 640; idx += 256){
    int el = idx / 10, c = idx - el*10;
    float z = zsh[el] + zsh[64+el] + zsh[128+el] + zsh[192+el];
    out[((size_t)blockIdx.x*64 + el)*10 + c] = z*fow[c] + fob[c];
  }
}

extern "C" void kernel_launch(void* const* d_in, const int* in_sizes, int n_in,
                              void* d_out, int out_size, void* d_ws, size_t ws_size,
                              hipStream_t stream) {
  (void)in_sizes; (void)n_in; (void)out_size; (void)ws_size;
  const float* x    = (const float*)d_in[0];
  const float* fcw  = (const float*)d_in[1];
  const float* fcb  = (const float*)d_in[2];
  const float* conv = (const float*)d_in[3];
  const float* pool = (const float*)d_in[4];
  const float* last = (const float*)d_in[5];
  const float* fow  = (const float*)d_in[6];
  const float* fob  = (const float*)d_in[7];
  float* out = (float*)d_out;

  char* ws = (char*)d_ws;
  float2* U   = (float2*)ws;                    // 512 KiB
  float*  red = (float*) (ws + 512*1024);       // 512 KiB
  float*  mt  = (float*) (ws + 1024*1024);      // 31 KiB padded (9*27*32 floats)

  kern_a       <<<1280, 256, 0, stream>>>(x, fcw, fcb, conv, pool, last, red, U);
  kern_m2      <<<256,  256, 0, stream>>>(U, mt);
  kern_contract<<<256,  256, 0, stream>>>(red, mt, fow, fob, out);
}

// Round 6
// 342.353 us; speedup vs baseline: 1.0649x; 1.0649x over previous
//
#include <hip/hip_runtime.h>
#include <math.h>

// ---------------- complex helpers ----------------
__device__ inline float2 cmul(float2 a, float2 b){
  return make_float2(a.x*b.x - a.y*b.y, a.x*b.y + a.y*b.x);
}
__device__ inline void cfma(float2& acc, float2 a, float2 b){
  acc.x += a.x*b.x - a.y*b.y;
  acc.y += a.x*b.y + a.y*b.x;
}

// u3(th, ph, lam) = [[c, -e^{i lam} s], [e^{i ph} s, e^{i(ph+lam)} c]]
__device__ inline void mk_u3(const float* p, float2& u00, float2& u01, float2& u10, float2& u11){
  float s, c;   sincosf(0.5f*p[0], &s, &c);
  float sl, cl; sincosf(p[1], &sl, &cl);            // ph
  float sm, cm; sincosf(p[2], &sm, &cm);            // lam
  float s2, c2; sincosf(p[1] + p[2], &s2, &c2);     // ph+lam
  u00 = make_float2(c, 0.f);
  u01 = make_float2(-s*cm, -s*sm);
  u10 = make_float2( s*cl,  s*sl);
  u11 = make_float2( c*c2,  c*s2);
}

__device__ inline void pauli2(int t, float2* m){ // 2x2, m[i*2+j]
  if (t == 0){ m[0]=make_float2(1,0); m[1]=make_float2(0,0);  m[2]=make_float2(0,0); m[3]=make_float2(1,0); }
  else if (t == 1){ m[0]=make_float2(0,0); m[1]=make_float2(1,0);  m[2]=make_float2(1,0); m[3]=make_float2(0,0); }
  else if (t == 2){ m[0]=make_float2(0,0); m[1]=make_float2(0,-1); m[2]=make_float2(0,1); m[3]=make_float2(0,0); }
  else            { m[0]=make_float2(1,0); m[1]=make_float2(0,0);  m[2]=make_float2(0,0); m[3]=make_float2(-1,0);}
}

// ---------------- gate program (base gates, build-only) ----------------
// types: 0=U3(w1), 1=ZZ(w1,w2), 2=YY, 3=XX, 4=CU3(ctrl=w1,tgt=w2), 5=PAULI kron wires(0,4), w1/w2 = pauli ids
// poff: <1000 conv, 1000..1999 pool-1000, >=2000 last-2000
struct GSpec { int type; int w1; int w2; int poff; };
#define NG 66
__device__ const GSpec gspec[NG] = {
  {0,0,0,  0},{0,2,0, 33},{1,0,2,  6},{2,0,2,  7},{3,0,2,  8},{0,0,0,  9},{0,2,0, 42},
  {0,1,0, 15},{0,3,0, 48},{1,1,3, 21},{2,1,3, 22},{3,1,3, 23},{0,1,0, 24},{0,3,0, 57},
  {0,4,0, 60},{0,6,0, 93},{1,4,6, 66},{2,4,6, 67},{3,4,6, 68},{0,4,0, 69},{0,6,0,102},
  {0,5,0, 75},{0,7,0,108},{1,5,7, 81},{2,5,7, 82},{3,5,7, 83},{0,5,0, 84},{0,7,0,117},
  {4,1,0,1000},{4,3,2,1003},{4,5,4,1006},{4,7,6,1009},
  {0,0,0,120},{0,2,0,153},{1,0,2,126},{2,0,2,127},{3,0,2,128},{0,0,0,129},{0,2,0,162},
  {0,4,0,180},{0,4,0,183},{0,4,0,186},{0,4,0,189},{0,4,0,192},
  {0,6,0,210},{0,6,0,213},{0,6,0,216},{0,6,0,219},{0,6,0,222},
  {4,2,0,1012},{4,6,4,1015},
  {5,1,0,2000},{5,2,0,2001},{5,3,0,2002},{5,3,1,2003},{5,0,1,2004},
  {5,1,1,2005},{5,2,1,2006},{5,2,2,2007},{5,3,2,2008},{5,0,2,2009},
  {5,1,2,2010},{5,1,3,2011},{5,2,3,2012},{5,3,3,2013},{5,0,3,2014},
};

// ---------------- 256-thread state-vector engine (S + gates in LDS) ----------------
// Wire w maps to bit (7-w) of the 256-index (wire 0 = MSB).
__device__ inline void apply1q_b(float2* S, int tid, int bit,
                                 float2 u00, float2 u01, float2 u10, float2 u11){
  if (tid < 128){
    int p  = tid;
    int k0 = ((p >> bit) << (bit+1)) | (p & ((1<<bit)-1));
    int k1 = k0 | (1 << bit);
    float2 a = S[k0], b = S[k1];
    float2 na = make_float2(u00.x*a.x - u00.y*a.y + u01.x*b.x - u01.y*b.y,
                            u00.x*a.y + u00.y*a.x + u01.x*b.y + u01.y*b.x);
    float2 nb = make_float2(u10.x*a.x - u10.y*a.y + u11.x*b.x - u11.y*b.y,
                            u10.x*a.y + u10.y*a.x + u11.x*b.y + u11.y*b.x);
    S[k0] = na; S[k1] = nb;
  }
  __syncthreads();
}

__device__ inline void apply2q_b(float2* S, int tid, int bitA, int bitB, const float2* G){
  if (tid < 64){
    int lane = tid;
    int hi = bitA > bitB ? bitA : bitB;
    int lo = bitA ^ bitB ^ hi;
    int t2  = ((lane >> lo) << (lo+1)) | (lane & ((1<<lo)-1));
    int k00 = ((t2   >> hi) << (hi+1)) | (t2   & ((1<<hi)-1));
    int mA = 1 << bitA, mB = 1 << bitB;
    int id[4] = { k00, k00|mB, k00|mA, k00|mA|mB };
    float2 v[4];
    #pragma unroll
    for (int r = 0; r < 4; r++) v[r] = S[id[r]];
    #pragma unroll
    for (int r = 0; r < 4; r++){
      float re = 0.f, im = 0.f;
      #pragma unroll
      for (int c = 0; c < 4; c++){
        float2 g = G[r*4 + c];
        re += g.x*v[c].x - g.y*v[c].y;
        im += g.x*v[c].y + g.y*v[c].x;
      }
      S[id[r]] = make_float2(re, im);
    }
  }
  __syncthreads();
}

// Kernel A: blocks 0..1023 = gemv (reduced = tanh(x @ fc_w^T + b));
//           blocks 1024..1279 = sim (block j simulates e_j; U[k*256+j] = amp k).
// 1280 blocks = exactly 5/CU co-resident (24 KiB LDS each, 120 KiB/CU) ->
// sim's ~3.4 us hides under the HBM-bound gemv instead of serializing.
__global__ __launch_bounds__(256) void kern_a(const float* __restrict__ x,
                                              const float* __restrict__ w,
                                              const float* __restrict__ b,
                                              const float* __restrict__ conv,
                                              const float* __restrict__ pool,
                                              const float* __restrict__ last,
                                              float* __restrict__ red,
                                              float2* __restrict__ U){
  __shared__ float4 smem4[1536];             // 24 KiB union
  const int tid = threadIdx.x;

  if (blockIdx.x < 1024){
    // ================= gemv =================
    float4* wl = smem4;                      // [8][192] float4, one K-quarter of w
    const int wave = tid >> 6, lane = tid & 63;
    const int rl = lane >> 5, co = lane & 31;
    const int row0 = blockIdx.x*16 + wave*4 + rl*2;   // rows row0, row0+1
    const float4* xp0 = (const float4*)(x + (size_t)row0*3072);
    const float4* xp1 = (const float4*)(x + (size_t)(row0+1)*3072);
    const float4* wp  = (const float4*)w;    // [8][768] float4
    float accA[8], accB[8];
    #pragma unroll
    for (int q = 0; q < 8; q++){ accA[q] = 0.f; accB[q] = 0.f; }

    for (int qt = 0; qt < 4; qt++){
      __syncthreads();
      #pragma unroll
      for (int i = 0; i < 6; i++){
        int idx = tid + 256*i;               // 0..1535
        int q = idx / 192, cc = idx - q*192;
        wl[idx] = wp[q*768 + qt*192 + cc];
      }
      __syncthreads();
      #pragma unroll
      for (int it = 0; it < 6; it++){
        int cl = it*32 + co;                 // 0..191 within tile
        float4 xa = xp0[qt*192 + cl];
        float4 xb = xp1[qt*192 + cl];
        #pragma unroll
        for (int q = 0; q < 8; q++){
          float4 wv = wl[q*192 + cl];
          accA[q] += wv.x*xa.x + wv.y*xa.y + wv.z*xa.z + wv.w*xa.w;
          accB[q] += wv.x*xb.x + wv.y*xb.y + wv.z*xb.z + wv.w*xb.w;
        }
      }
    }

    #pragma unroll
    for (int q = 0; q < 8; q++){
      float va = accA[q], vb = accB[q];
      va += __shfl_xor(va, 1);  vb += __shfl_xor(vb, 1);
      va += __shfl_xor(va, 2);  vb += __shfl_xor(vb, 2);
      va += __shfl_xor(va, 4);  vb += __shfl_xor(vb, 4);
      va += __shfl_xor(va, 8);  vb += __shfl_xor(vb, 8);
      va += __shfl_xor(va, 16); vb += __shfl_xor(vb, 16);
      accA[q] = va; accB[q] = vb;
    }
    if (co == 0){
      float4 a0 = make_float4(tanhf(accA[0]+b[0]), tanhf(accA[1]+b[1]),
                              tanhf(accA[2]+b[2]), tanhf(accA[3]+b[3]));
      float4 a1 = make_float4(tanhf(accA[4]+b[4]), tanhf(accA[5]+b[5]),
                              tanhf(accA[6]+b[6]), tanhf(accA[7]+b[7]));
      float4* rpA = (float4*)(red + (size_t)row0*8);
      rpA[0] = a0; rpA[1] = a1;
      float4 b0 = make_float4(tanhf(accB[0]+b[0]), tanhf(accB[1]+b[1]),
                              tanhf(accB[2]+b[2]), tanhf(accB[3]+b[3]));
      float4 b1 = make_float4(tanhf(accB[4]+b[4]), tanhf(accB[5]+b[5]),
                              tanhf(accB[6]+b[6]), tanhf(accB[7]+b[7]));
      float4* rpB = (float4*)(red + (size_t)(row0+1)*8);
      rpB[0] = b0; rpB[1] = b1;
    }
    return;
  }

  // ================= sim =================
  const int j = blockIdx.x - 1024;
  float2* Gt = (float2*)smem4;               // 66*16
  float2* Ft = Gt + NG*16;                   // 14*16: 0-3 C0..C3, 4 C4, 5 S0, 6 S1, 7-12 P0..P5, 13 L
  float2* Ms = Ft + 14*16;                   // 7*16 scratch
  float2* S  = Ms + 7*16;                    // 256 amplitudes

  // ---- build all base gate matrices into LDS ----
  for (int g = tid; g < NG; g += 256){
    GSpec sp = gspec[g];
    const float* base;
    if (sp.poff >= 2000)      base = last + (sp.poff - 2000);
    else if (sp.poff >= 1000) base = pool + (sp.poff - 1000);
    else                      base = conv + sp.poff;
    float2 G[16];
    #pragma unroll
    for (int i = 0; i < 16; i++) G[i] = make_float2(0.f, 0.f);
    if (sp.type == 0){
      float2 a,bb,c,d; mk_u3(base,a,bb,c,d);
      G[0]=a; G[1]=bb; G[2]=c; G[3]=d;
    } else if (sp.type == 1){ // ZZ
      float s,co; sincosf(0.5f*base[0], &s, &co);
      G[0]=make_float2(co,-s); G[5]=make_float2(co,s); G[10]=make_float2(co,s); G[15]=make_float2(co,-s);
    } else if (sp.type == 2){ // YY
      float s,co; sincosf(0.5f*base[0], &s, &co);
      G[0]=G[5]=G[10]=G[15]=make_float2(co,0.f);
      G[3]=make_float2(0.f,s); G[6]=make_float2(0.f,-s); G[9]=make_float2(0.f,-s); G[12]=make_float2(0.f,s);
    } else if (sp.type == 3){ // XX
      float s,co; sincosf(0.5f*base[0], &s, &co);
      G[0]=G[5]=G[10]=G[15]=make_float2(co,0.f);
      G[3]=G[6]=G[9]=G[12]=make_float2(0.f,-s);
    } else if (sp.type == 4){ // CU3
      float2 a,bb,c,d; mk_u3(base,a,bb,c,d);
      G[0]=make_float2(1.f,0.f); G[5]=make_float2(1.f,0.f);
      G[10]=a; G[11]=bb; G[14]=c; G[15]=d;
    } else { // PAULI word: G = cos*I - i sin*(A ⊗ B)
      float s,co; sincosf(0.5f*base[0], &s, &co);
      float2 A2[4], B2[4]; pauli2(sp.w1,A2); pauli2(sp.w2,B2);
      #pragma unroll
      for (int i1 = 0; i1 < 2; i1++)
      #pragma unroll
      for (int i2 = 0; i2 < 2; i2++)
      #pragma unroll
      for (int j1 = 0; j1 < 2; j1++)
      #pragma unroll
      for (int j2 = 0; j2 < 2; j2++){
        float2 Pv = cmul(A2[i1*2+j1], B2[i2*2+j2]);
        int rr = i1*2+i2, cc = j1*2+j2;
        G[rr*4+cc] = make_float2((rr==cc ? co : 0.f) + s*Pv.y, -s*Pv.x);
      }
    }
    #pragma unroll
    for (int i = 0; i < 16; i++) Gt[g*16 + i] = G[i];
  }
  __syncthreads();

  const int fe = tid & 15;
  const int fr = fe >> 2, fc = fe & 3;

  // ---- fusion sub-phase 1: L1 conv pairs (threads 0..63, pair p = tid>>4) ----
  {
    const bool act = tid < 64;
    const int p  = tid >> 4;
    const int gb = p*7;
    if (act){
      float2 va = Gt[gb*16     + (fr>>1)*2 + (fc>>1)];
      float2 vb = Gt[(gb+1)*16 + (fr&1)*2  + (fc&1)];
      Ms[p*16 + fe] = cmul(va, vb);
    }
    __syncthreads();
    for (int s = 0; s < 3; s++){
      float2 acc = make_float2(0.f, 0.f);
      if (act){
        #pragma unroll
        for (int k = 0; k < 4; k++)
          cfma(acc, Gt[(gb+2+s)*16 + fr*4 + k], Ms[p*16 + k*4 + fc]);
      }
      __syncthreads();
      if (act) Ms[p*16 + fe] = acc;
      __syncthreads();
    }
    if (act){
      float2 ka = Gt[(gb+5)*16 + (fr>>1)*2 + (fc>>1)];
      float2 kb = Gt[(gb+6)*16 + (fr&1)*2  + (fc&1)];
      Ft[p*16 + fe] = cmul(ka, kb);
    }
    __syncthreads();
    float2 acc2 = make_float2(0.f, 0.f);
    if (act){
      #pragma unroll
      for (int k = 0; k < 4; k++)
        cfma(acc2, Ft[p*16 + fr*4 + k], Ms[p*16 + k*4 + fc]);
    }
    __syncthreads();
    if (act) Ft[p*16 + fe] = acc2;
    __syncthreads();
  }

  // ---- fusion sub-phase 2 (concurrent groups):
  //   tid 0-15: C4 (g32..g38); tid 16-31: L (g51..g65); tid 32-39: S0/S1 (g39..g48)
  {
    const int grp = tid >> 4;
    if (grp == 0){
      float2 va = Gt[32*16 + (fr>>1)*2 + (fc>>1)];
      float2 vb = Gt[33*16 + (fr&1)*2  + (fc&1)];
      Ms[4*16 + fe] = cmul(va, vb);
    } else if (grp == 1){
      Ms[5*16 + fe] = Gt[51*16 + fe];
    } else if (tid < 40){
      int t = (tid-32)>>2, e2 = (tid-32)&3;
      Ms[6*16 + t*4 + e2] = Gt[(39+5*t)*16 + e2];
    }
    __syncthreads();
    for (int s = 1; s <= 14; s++){
      float2 val = make_float2(0.f, 0.f);
      int wf = 0, dst = 0;   // wf: 1 -> Ms, 2 -> Ft
      if (grp == 0){
        if (s <= 3){            // ZZ (g34), YY (g35), XX (g36)
          #pragma unroll
          for (int k = 0; k < 4; k++)
            cfma(val, Gt[(33+s)*16 + fr*4 + k], Ms[4*16 + k*4 + fc]);
          wf = 1; dst = 4*16 + fe;
        } else if (s == 4){     // K2 = kron(g37, g38) -> temp in Ms[0]
          float2 ka = Gt[37*16 + (fr>>1)*2 + (fc>>1)];
          float2 kb = Gt[38*16 + (fr&1)*2  + (fc&1)];
          val = cmul(ka, kb); wf = 1; dst = 0*16 + fe;
        } else if (s == 5){     // C4 = K2 * M
          #pragma unroll
          for (int k = 0; k < 4; k++)
            cfma(val, Ms[0*16 + fr*4 + k], Ms[4*16 + k*4 + fc]);
          wf = 2; dst = 4*16 + fe;
        }
      } else if (grp == 1){     // L = g65 * ... * g51
        #pragma unroll
        for (int k = 0; k < 4; k++)
          cfma(val, Gt[(51+s)*16 + fr*4 + k], Ms[5*16 + k*4 + fc]);
        if (s == 14){ wf = 2; dst = 13*16 + fe; }
        else        { wf = 1; dst = 5*16 + fe; }
      } else if (tid < 40 && s <= 4){  // 2x2 chains, wires 4 and 6
        int t = (tid-32)>>2, e2 = (tid-32)&3, r2 = e2>>1, c2 = e2&1;
        #pragma unroll
        for (int k = 0; k < 2; k++)
          cfma(val, Gt[(39+5*t+s)*16 + r2*2 + k], Ms[6*16 + t*4 + k*2 + c2]);
        if (s == 4){ wf = 2; dst = (5+t)*16 + e2; }
        else       { wf = 1; dst = 6*16 + t*4 + e2; }
      }
      __syncthreads();
      if (wf == 1) Ms[dst] = val;
      else if (wf == 2) Ft[dst] = val;
      __syncthreads();
    }
    // CU3 copies: Ft slots 7..12 <- Gt {28,29,30,31,49,50}
    for (int idx = tid; idx < 96; idx += 256){
      int q = idx >> 4, e = idx & 15;
      int gid = (q < 4) ? (28+q) : (q == 4 ? 49 : 50);
      Ft[(7+q)*16 + e] = Gt[gid*16 + e];
    }
  }
  __syncthreads();

  // ---- state init ----
  S[tid] = make_float2(tid==j ? 1.f : 0.f, 0.f);
  __syncthreads();

  // ---- 14 fused applies (original gate order preserved; disjoint-wire gates commute) ----
  apply2q_b(S, tid, 7, 5, &Ft[0*16]);   // C0 (0,2)
  apply2q_b(S, tid, 6, 4, &Ft[1*16]);   // C1 (1,3)
  apply2q_b(S, tid, 3, 1, &Ft[2*16]);   // C2 (4,6)
  apply2q_b(S, tid, 2, 0, &Ft[3*16]);   // C3 (5,7)
  apply2q_b(S, tid, 6, 7, &Ft[7*16]);   // P0 CU3(1,0)
  apply2q_b(S, tid, 4, 5, &Ft[8*16]);   // P1 CU3(3,2)
  apply2q_b(S, tid, 2, 3, &Ft[9*16]);   // P2 CU3(5,4)
  apply2q_b(S, tid, 0, 1, &Ft[10*16]);  // P3 CU3(7,6)
  apply2q_b(S, tid, 7, 5, &Ft[4*16]);   // C4 (0,2)
  apply1q_b(S, tid, 3, Ft[5*16+0], Ft[5*16+1], Ft[5*16+2], Ft[5*16+3]);  // S0 wire 4
  apply1q_b(S, tid, 1, Ft[6*16+0], Ft[6*16+1], Ft[6*16+2], Ft[6*16+3]);  // S1 wire 6
  apply2q_b(S, tid, 5, 7, &Ft[11*16]);  // P4 CU3(2,0)
  apply2q_b(S, tid, 1, 3, &Ft[12*16]);  // P5 CU3(6,4)
  apply2q_b(S, tid, 7, 3, &Ft[13*16]);  // L (0,4)

  U[tid*256 + j] = S[tid];
}

// K2: block xm: D[i] = sum_k z_k Re(conj(U_ki) U_k(i^xm)); FWHT over i; store PADDED m table:
// layout mt[(h*27+mm)*32 + l] (h=3d7+d6, mm=9d5+3d4+d3, l=9d2+3d1+d0) -> per-bit weights
// {1,3,9,32,96,288,864,2592}. Pads (l=27..31) zeroed so contract can stage raw float4s.
__global__ __launch_bounds__(256) void kern_m2(const float2* __restrict__ U,
                                               float* __restrict__ mt){
  __shared__ float dsh[256];
  const int xm = blockIdx.x, i = threadIdx.x;
  if (xm == 0){                      // zero the 9*27*5 pad slots (poison otherwise)
    for (int z = i; z < 1215; z += 256){
      int hm = z/5, l = z - hm*5;
      mt[hm*32 + 27 + l] = 0.f;
    }
  }
  const int j2 = i ^ xm;
  float acc = 0.f;
  #pragma unroll 4
  for (int k = 0; k < 128; k++){
    float2 ui0 = U[k*256 + i];
    float2 uj0 = U[k*256 + j2];
    float2 ui1 = U[(k+128)*256 + i];
    float2 uj1 = U[(k+128)*256 + j2];
    acc += (ui0.x*uj0.x + ui0.y*uj0.y) - (ui1.x*uj1.x + ui1.y*uj1.y);
  }
  dsh[i] = acc;
  __syncthreads();
  for (int bit = 1; bit < 256; bit <<= 1){
    float mine = dsh[i], other = dsh[i ^ bit];
    __syncthreads();
    dsh[i] = (i & bit) ? (other - mine) : (mine + other);
    __syncthreads();
  }
  if ((i & xm) == 0){
    int idx = 0;
    #pragma unroll
    for (int b2 = 0; b2 < 8; b2++){
      const int w8 = (b2==0)?1:(b2==1)?3:(b2==2)?9:(b2==3)?32:
                     (b2==4)?96:(b2==5)?288:(b2==6)?864:2592;
      int dg = ((xm >> b2) & 1) ? 1 : (((i >> b2) & 1) ? 2 : 0);
      idx += dg * w8;
    }
    mt[idx] = dsh[i] * (1.0f/256.0f);
  }
}

// K4: z0[e] = sum over 3^8 Pauli strings m_p * prod t_w; logits = z0*fow + fob.
// mt staged in LDS (flat 31 KiB copy; already padded by m2): ds_read_b128 with
// compile-time offset: immediates (no 64-bit VALU addressing, unlike global reads).
__global__ __launch_bounds__(256) void kern_contract(const float* __restrict__ red,
                                                     const float* __restrict__ mt,
                                                     const float* __restrict__ fow,
                                                     const float* __restrict__ fob,
                                                     float* __restrict__ out){
  __shared__ float mtl[9*27*32];
  __shared__ float zsh[4*64];
  const int tid = threadIdx.x;
  {
    float4* d4 = (float4*)mtl;
    const float4* s4 = (const float4*)mt;
    for (int idx = tid; idx < 1944; idx += 256) d4[idx] = s4[idx];
  }
  const int wave = tid >> 6, lane = tid & 63;
  const int e = blockIdx.x*64 + lane;
  const float4* rp = (const float4*)(red + (size_t)e*8);
  float4 r0 = rp[0], r1 = rp[1];
  __syncthreads();

  float rr[8] = {r0.x, r0.y, r0.z, r0.w, r1.x, r1.y, r1.z, r1.w};
  float sn[8], cs[8];
  #pragma unroll
  for (int q = 0; q < 8; q++) sincosf(rr[q], &sn[q], &cs[q]);
  // digit d at bit b: 0 -> 1, 1 -> sin(r[7-b]) (X), 2 -> cos(r[7-b]) (Z)
  float f0[3] = {1.f, sn[7], cs[7]};
  float f1[3] = {1.f, sn[6], cs[6]};
  float f2[3] = {1.f, sn[5], cs[5]};
  float g27[32];
  #pragma unroll
  for (int z = 27; z < 32; z++) g27[z] = 0.f;
  #pragma unroll
  for (int d2 = 0; d2 < 3; d2++)
  #pragma unroll
  for (int d1 = 0; d1 < 3; d1++)
  #pragma unroll
  for (int d0 = 0; d0 < 3; d0++)
    g27[9*d2 + 3*d1 + d0] = f2[d2]*f1[d1]*f0[d0];
  float4 glo4[8];
  #pragma unroll
  for (int v = 0; v < 8; v++)
    glo4[v] = make_float4(g27[4*v], g27[4*v+1], g27[4*v+2], g27[4*v+3]);
  float f3[3] = {1.f, sn[4], cs[4]};
  float f4[3] = {1.f, sn[3], cs[3]};
  float f5[3] = {1.f, sn[2], cs[2]};
  float gmid[27];
  #pragma unroll
  for (int d5 = 0; d5 < 3; d5++)
  #pragma unroll
  for (int d4 = 0; d4 < 3; d4++)
  #pragma unroll
  for (int d3 = 0; d3 < 3; d3++)
    gmid[9*d5 + 3*d4 + d3] = f5[d5]*f4[d4]*f3[d3];
  float f6[3] = {1.f, sn[1], cs[1]};
  float f7[3] = {1.f, sn[0], cs[0]};
  float ghi[9];
  #pragma unroll
  for (int d7 = 0; d7 < 3; d7++)
  #pragma unroll
  for (int d6 = 0; d6 < 3; d6++)
    ghi[3*d7 + d6] = f7[d7]*f6[d6];

  // wave h-partition: {0,1,2},{3,4},{5,6},{7,8}
  const int hbeg = (wave==0) ? 0 : (wave==1) ? 3 : (wave==2) ? 5 : 7;
  const int hend = hbeg + ((wave==0) ? 3 : 2);
  float part = 0.f;
  for (int h = hbeg; h < hend; h++){
    float ha = 0.f, hb = 0.f;
    #pragma unroll 3
    for (int mm = 0; mm < 27; mm++){
      const float4* mp = (const float4*)&mtl[(h*27 + mm) << 5];
      float d0 = 0.f, d1 = 0.f;
      #pragma unroll
      for (int v = 0; v < 8; v += 2){
        float4 m0 = mp[v], m1 = mp[v+1];
        d0 += m0.x*glo4[v].x   + m0.y*glo4[v].y   + m0.z*glo4[v].z   + m0.w*glo4[v].w;
        d1 += m1.x*glo4[v+1].x + m1.y*glo4[v+1].y + m1.z*glo4[v+1].z + m1.w*glo4[v+1].w;
      }
      float term = (d0 + d1) * gmid[mm];
      if (mm & 1) hb += term; else ha += term;
    }
    part += (ha + hb) * ghi[h];
  }
  zsh[wave*64 + lane] = part;
  __syncthreads();

  for (int idx = tid; idx < 640; idx += 256){
    int el = idx / 10, c = idx - el*10;
    float z = zsh[el] + zsh[64+el] + zsh[128+el] + zsh[192+el];
    out[((size_t)blockIdx.x*64 + el)*10 + c] = z*fow[c] + fob[c];
  }
}

extern "C" void kernel_launch(void* const* d_in, const int* in_sizes, int n_in,
                              void* d_out, int out_size, void* d_ws, size_t ws_size,
                              hipStream_t stream) {
  (void)in_sizes; (void)n_in; (void)out_size; (void)ws_size;
  const float* x    = (const float*)d_in[0];
  const float* fcw  = (const float*)d_in[1];
  const float* fcb  = (const float*)d_in[2];
  const float* conv = (const float*)d_in[3];
  const float* pool = (const float*)d_in[4];
  const float* last = (const float*)d_in[5];
  const float* fow  = (const float*)d_in[6];
  const float* fob  = (const float*)d_in[7];
  float* out = (float*)d_out;

  char* ws = (char*)d_ws;
  float2* U   = (float2*)ws;                    // 512 KiB
  float*  red = (float*) (ws + 512*1024);       // 512 KiB
  float*  mt  = (float*) (ws + 1024*1024);      // 31 KiB padded (9*27*32 floats)

  kern_a       <<<1280, 256, 0, stream>>>(x, fcw, fcb, conv, pool, last, red, U);
  kern_m2      <<<256,  256, 0, stream>>>(U, mt);
  kern_contract<<<256,  256, 0, stream>>>(red, mt, fow, fob, out);
}